// Round 21
// baseline (54.017 us; speedup 1.0000x reference)
//
#include <hip/hip_runtime.h>
#include <hip/hip_bf16.h>
#include <stdint.h>

#define NROWS 8192
#define BROWS 4096
#define LN2 0.6931471805599453f
#define FSC 8.944507e-4f        // (1/T)*log2(e) / 127^2, T=0.1
#define KMAD 7503               // round(FSC * 2^23)
#define CBITS 1064989150        // (127 - 0.0434) * 2^23  (Schraudolph exp2)
#define NBLK 2112               // sum_{it=0}^{127} ceil((128-it)/4) = 8*264

typedef __attribute__((ext_vector_type(4))) int i32x4;

__device__ inline void gload_lds16(const void* g, void* l) {
  __builtin_amdgcn_global_load_lds((const __attribute__((address_space(1))) void*)g,
                                   (__attribute__((address_space(3))) void*)l,
                                   16, 0, 0);
}

// Kernel A: L2-normalize rows, quantize to i8; store qss=sum(q^2); zero denom/out.
// First 2112 threads also precompute ksim's block->(strip,chunk) table.
__global__ __launch_bounds__(256) void knorm(const float* __restrict__ zi,
                                             const float* __restrict__ zj,
                                             int* __restrict__ reps,   // i8 packed
                                             int* __restrict__ qss,
                                             int* __restrict__ tab,
                                             float* __restrict__ denom,
                                             float* __restrict__ out) {
  int w = threadIdx.x >> 6, l = threadIdx.x & 63;
  int row = blockIdx.x * 4 + w;
  const float* src = (row < BROWS) ? (zi + (size_t)row * 256)
                                   : (zj + (size_t)(row - BROWS) * 256);
  float4 v = ((const float4*)src)[l];
  float ss = v.x * v.x + v.y * v.y + v.z * v.z + v.w * v.w;
#pragma unroll
  for (int m = 1; m < 64; m <<= 1) ss += __shfl_xor(ss, m, 64);
  float sc = 127.0f / fmaxf(sqrtf(ss), 1e-12f);
  int q0 = __float2int_rn(v.x * sc), q1 = __float2int_rn(v.y * sc);
  int q2 = __float2int_rn(v.z * sc), q3 = __float2int_rn(v.w * sc);
  reps[(size_t)row * 64 + l] =
      (q0 & 255) | ((q1 & 255) << 8) | ((q2 & 255) << 16) | ((q3 & 255) << 24);
  int qs = q0 * q0 + q1 * q1 + q2 * q2 + q3 * q3;
#pragma unroll
  for (int m = 1; m < 64; m <<= 1) qs += __shfl_xor(qs, m, 64);
  if (l == 0) { denom[row] = 0.f; qss[row] = qs; }
  if (row == 0 && l == 0) out[0] = 0.f;

  int gid = blockIdx.x * 256 + threadIdx.x;
  if (gid < NBLK) {
    int orig = (gid & 7) * 264 + (gid >> 3);   // XCD-bijective swizzle
    int rem = orig, it = 0, ch;
    while (rem >= (ch = (128 - it + 3) >> 2)) { rem -= ch; ++it; }
    tab[gid] = it | (rem << 16);
  }
}

// Kernel B: barrier-free upper-tri sim, i8 MFMA 16x16x64, ONE WAVE PER BLOCK.
// Block = 64-row strip x 256-col chunk (2112 blocks); RING-3 of 8KB 32-col
// tiles with DEPTH-2 prefetch: every stage has ~2 phases to land, so the
// vmcnt wait is ~free. Column sums in LDS (DS ops - invisible to vmcnt;
// R20's direct global atomics polluted the vmcnt gate). Schraudolph exp2.
__global__ __launch_bounds__(64, 2) void ksim(const int* __restrict__ reps_,
                                              const int* __restrict__ tab,
                                              float* __restrict__ denom,
                                              float* __restrict__ pos) {
  __shared__ uint4 smem[3][512];     // 3 x 32 reps-rows x 256 B = 24 KB ring
  __shared__ float colacc[256];      // 1 KB (single wave: plain adds)
  int l = threadIdx.x;               // 0..63
  int kgrp = l >> 4;

  int v = tab[blockIdx.x];
  int it = v & 0xffff, q = v >> 16;
  int rowbase = it * 64;
  int cs0 = rowbase + q * 256;
  int len = NROWS - cs0; if (len > 256) len = 256;
  int ntile = len >> 5;              // 2,4,6,8

  colacc[l] = 0.f; colacc[l + 64] = 0.f;
  colacc[l + 128] = 0.f; colacc[l + 192] = 0.f;

  // ---- staging: 32 reps-rows x 256B -> 8KB ring slot; linear LDS dest,
  //      4-bit XOR pre-swizzled source (read-side involution) ----
  auto stage = [&](int slot, int colbase) {
#pragma unroll
    for (int i = 0; i < 8; ++i) {
      int lr = i * 4 + (l >> 4);     // local row 0..31
      int kb = ((l & 15) * 16) ^ ((lr & 15) << 4);
      gload_lds16((const char*)reps_ + (size_t)(colbase + lr) * 256 + kb,
                  (void*)&smem[slot][i * 64]);
    }
  };
  stage(0, cs0);

  // ---- A fragments: 64-row strip; lane holds row rowbase+fr*16+(l&15) ----
  i32x4 a[4][4];
  {
    const uint4* r4 = (const uint4*)reps_;
    int arow = rowbase + (l & 15);
#pragma unroll
    for (int fr = 0; fr < 4; ++fr)
#pragma unroll
      for (int kk = 0; kk < 4; ++kk)
        a[fr][kk] = __builtin_bit_cast(i32x4,
            r4[(size_t)(arow + fr * 16) * 16 + kk * 4 + kgrp]);
  }
  if (ntile > 1) stage(1, cs0 + 32);

  float rowsum[4][4];
#pragma unroll
  for (int fr = 0; fr < 4; ++fr)
#pragma unroll
    for (int r = 0; r < 4; ++r) rowsum[fr][r] = 0.f;

  int r0 = rowbase + kgrp * 4;
  int slot = 0;                      // = t % 3, maintained incrementally
  const int kmad = KMAD;             // SGPR
  const int cbits = CBITS;           // VGPR (2nd const; 1-SGPR rule)

  for (int t = 0; t < ntile; ++t) {
    // depth-2 prefetch, then wait only for stage(t) (+A at t=0)
    if (t + 2 < ntile) {
      int ns = slot + 2; if (ns >= 3) ns -= 3;
      stage(ns, cs0 + 32 * (t + 2));
      asm volatile("s_waitcnt vmcnt(16)" ::: "memory");  // s(t+1)+s(t+2) in flight
    } else if (t + 1 < ntile) {
      asm volatile("s_waitcnt vmcnt(8)" ::: "memory");   // s(t+1) in flight
    } else {
      asm volatile("s_waitcnt vmcnt(0)" ::: "memory");
    }
    __builtin_amdgcn_sched_barrier(0);

    const char* bb = (const char*)&smem[0][0] + slot * 8192;
    i32x4 acc[4][2];
    const i32x4 zero = {0, 0, 0, 0};
    __builtin_amdgcn_s_setprio(1);
#pragma unroll
    for (int kk = 0; kk < 4; ++kk) {
      i32x4 bf[2];
#pragma unroll
      for (int fc = 0; fc < 2; ++fc) {
        int lr = (l & 15) + fc * 16;
        bf[fc] = *(const i32x4*)(bb + lr * 256 + ((((kk * 4 + kgrp) ^ (lr & 15))) << 4));
      }
#pragma unroll
      for (int fr = 0; fr < 4; ++fr)
#pragma unroll
        for (int fc = 0; fc < 2; ++fc) {
          if (kk == 0)
            acc[fr][fc] = __builtin_amdgcn_mfma_i32_16x16x64_i8(a[fr][0], bf[fc], zero, 0, 0, 0);
          else
            acc[fr][fc] = __builtin_amdgcn_mfma_i32_16x16x64_i8(a[fr][kk], bf[fc], acc[fr][fc], 0, 0, 0);
        }
    }
    __builtin_amdgcn_s_setprio(0);

    // ---- epilogue: e = bitcast(mad_i24(I, K, C)); rowsum + colacc (LDS) ----
    int cb = cs0 + 32 * t;
    bool docol = !(q == 0 && t < 2);        // diag 64-col window: rowsum only
    bool dopos = (q == 16) && (t < 2);
    float cp0 = 0.f, cp1 = 0.f;
#pragma unroll
    for (int fr = 0; fr < 4; ++fr)
#pragma unroll
      for (int fc = 0; fc < 2; ++fc)
#pragma unroll
        for (int r = 0; r < 4; ++r) {
          int I = acc[fr][fc][r];
          int ib;
          asm("v_mad_i32_i24 %0, %1, %2, %3"
              : "=v"(ib) : "v"(I), "s"(kmad), "v"(cbits));
          float e = __builtin_bit_cast(float, ib);
          if (dopos) {
            int rg = r0 + fr * 16 + r;
            int cg = cb + (l & 15) + fc * 16;
            if (cg == rg + BROWS) pos[rg] = (float)I * FSC;
          }
          rowsum[fr][r] += e;
          if (fc == 0) cp0 += e; else cp1 += e;
        }
    if (docol) {
      cp0 += __shfl_xor(cp0, 16, 64); cp0 += __shfl_xor(cp0, 32, 64);
      cp1 += __shfl_xor(cp1, 16, 64); cp1 += __shfl_xor(cp1, 32, 64);
      if (l < 16) {
        int off = (cb - cs0) + l;
        colacc[off] += cp0;
        colacc[off + 16] += cp1;
      }
    }
    ++slot; if (slot >= 3) slot = 0;
  }

  // ---- row sums: reduce 16 col-lanes; 4 lanes issue global atomics ----
#pragma unroll
  for (int fr = 0; fr < 4; ++fr)
#pragma unroll
    for (int r = 0; r < 4; ++r) {
      float vv = rowsum[fr][r];
      vv += __shfl_xor(vv, 1, 64);
      vv += __shfl_xor(vv, 2, 64);
      vv += __shfl_xor(vv, 4, 64);
      vv += __shfl_xor(vv, 8, 64);
      if ((l & 15) == 0) atomicAdd(&denom[r0 + fr * 16 + r], vv);
    }

  // ---- col sums: flush colacc, one atomic per nonzero column ----
#pragma unroll
  for (int i = 0; i < 4; ++i) {
    int off = l + 64 * i;
    float vv = colacc[off];
    if (vv != 0.f) atomicAdd(&denom[cs0 + off], vv);
  }
}

// Kernel F: subtract the (bit-identical) diagonal term, then
// + (1/N) * sum_i (log(denom_i) - pos_{i mod B} * ln2)
__global__ __launch_bounds__(256) void kfin(const float* __restrict__ denom,
                                            const float* __restrict__ pos,
                                            const int* __restrict__ qss,
                                            float* __restrict__ out) {
  int i = blockIdx.x * 256 + threadIdx.x;
  int ib = qss[i] * KMAD + CBITS;           // same int formula as ksim's mad_i24
  float diag_e = __builtin_bit_cast(float, ib);
  float v = (logf(denom[i] - diag_e) - pos[i & 4095] * LN2) * (1.0f / 8192.0f);
#pragma unroll
  for (int m = 1; m < 64; m <<= 1) v += __shfl_xor(v, m, 64);
  __shared__ float part[4];
  if ((threadIdx.x & 63) == 0) part[threadIdx.x >> 6] = v;
  __syncthreads();
  if (threadIdx.x == 0)
    atomicAdd(out, part[0] + part[1] + part[2] + part[3]);
}

extern "C" void kernel_launch(void* const* d_in, const int* in_sizes, int n_in,
                              void* d_out, int out_size, void* d_ws, size_t ws_size,
                              hipStream_t stream) {
  (void)in_sizes; (void)n_in; (void)out_size; (void)ws_size;
  const float* zi = (const float*)d_in[0];
  const float* zj = (const float*)d_in[1];
  float* out = (float*)d_out;
  char* ws = (char*)d_ws;
  int* reps    = (int*)ws;                                    // 2 MB (i8 packed)
  float* denom = (float*)(ws + 2097152);                      // 32 KB
  float* pos   = (float*)(ws + 2097152 + 32768);              // 16 KB
  int* qss     = (int*)(ws + 2097152 + 32768 + 16384);        // 32 KB
  int* tab     = (int*)(ws + 2097152 + 32768 + 16384 + 32768); // 8.25 KB

  knorm<<<2048, 256, 0, stream>>>(zi, zj, reps, qss, tab, denom, out);
  ksim<<<NBLK, 64, 0, stream>>>(reps, tab, denom, pos);
  kfin<<<32, 256, 0, stream>>>(denom, pos, qss, out);
}

// Round 22
// 40.531 us; speedup vs baseline: 1.3327x; 1.3327x over previous
//
#include <hip/hip_runtime.h>
#include <hip/hip_bf16.h>
#include <stdint.h>

#define NROWS 8192
#define BROWS 4096
#define LN2 0.6931471805599453f
#define FSC 8.944507e-4f        // (1/T)*log2(e) / 127^2, T=0.1
#define KMAD 7503               // round(FSC * 2^23)
#define CBITS 1064989150        // (127 - 0.0434) * 2^23  (Schraudolph exp2)
#define NBLK 2112               // sum_{it=0}^{127} ceil((128-it)/4) = 8*264

typedef __attribute__((ext_vector_type(4))) int i32x4;

__device__ inline void gload_lds16(const void* g, void* l) {
  __builtin_amdgcn_global_load_lds((const __attribute__((address_space(1))) void*)g,
                                   (__attribute__((address_space(3))) void*)l,
                                   16, 0, 0);
}

// Kernel A: L2-normalize rows, quantize to i8; store qss=sum(q^2); zero denom/out.
// First 2112 threads also precompute ksim's block->(strip,chunk) table.
__global__ __launch_bounds__(256) void knorm(const float* __restrict__ zi,
                                             const float* __restrict__ zj,
                                             int* __restrict__ reps,   // i8 packed
                                             int* __restrict__ qss,
                                             int* __restrict__ tab,
                                             float* __restrict__ denom,
                                             float* __restrict__ out) {
  int w = threadIdx.x >> 6, l = threadIdx.x & 63;
  int row = blockIdx.x * 4 + w;
  const float* src = (row < BROWS) ? (zi + (size_t)row * 256)
                                   : (zj + (size_t)(row - BROWS) * 256);
  float4 v = ((const float4*)src)[l];
  float ss = v.x * v.x + v.y * v.y + v.z * v.z + v.w * v.w;
#pragma unroll
  for (int m = 1; m < 64; m <<= 1) ss += __shfl_xor(ss, m, 64);
  float sc = 127.0f / fmaxf(sqrtf(ss), 1e-12f);
  int q0 = __float2int_rn(v.x * sc), q1 = __float2int_rn(v.y * sc);
  int q2 = __float2int_rn(v.z * sc), q3 = __float2int_rn(v.w * sc);
  reps[(size_t)row * 64 + l] =
      (q0 & 255) | ((q1 & 255) << 8) | ((q2 & 255) << 16) | ((q3 & 255) << 24);
  int qs = q0 * q0 + q1 * q1 + q2 * q2 + q3 * q3;
#pragma unroll
  for (int m = 1; m < 64; m <<= 1) qs += __shfl_xor(qs, m, 64);
  if (l == 0) { denom[row] = 0.f; qss[row] = qs; }
  if (row == 0 && l == 0) out[0] = 0.f;

  int gid = blockIdx.x * 256 + threadIdx.x;
  if (gid < NBLK) {
    int orig = (gid & 7) * 264 + (gid >> 3);   // XCD-bijective swizzle
    int rem = orig, it = 0, ch;
    while (rem >= (ch = (128 - it + 3) >> 2)) { rem -= ch; ++it; }
    tab[gid] = it | (rem << 16);
  }
}

// Kernel B: R16's kernel verbatim (best measured: ksim ~28us) + tab lookup.
// Barrier-free upper-tri sim, i8 MFMA 16x16x64, ONE WAVE PER BLOCK.
// Block = 64-row strip x 256-col chunk (2112 blocks); 32-col dbuf LDS tiles
// (2x8KB), counted vmcnt(8). Schraudolph exp2 epilogue; diagonal included,
// subtracted bit-identically in kfin. Column sums in LDS colacc (DS ops --
// invisible to the vmcnt gate; R20 proved direct global atomics poison it).
__global__ __launch_bounds__(64, 2) void ksim(const int* __restrict__ reps_,
                                              const int* __restrict__ tab,
                                              float* __restrict__ denom,
                                              float* __restrict__ pos) {
  __shared__ uint4 smem[2][512];     // 2 x 32 reps-rows x 256 B = 16 KB
  __shared__ float colacc[256];      // 1 KB (single wave: plain adds)
  int l = threadIdx.x;               // 0..63
  int kgrp = l >> 4;

  int v = tab[blockIdx.x];
  int it = v & 0xffff, q = v >> 16;
  int rowbase = it * 64;
  int cs0 = rowbase + q * 256;
  int len = NROWS - cs0; if (len > 256) len = 256;
  int ntile = len >> 5;              // 2,4,6,8

#pragma unroll
  for (int i = 0; i < 4; ++i) colacc[l + 64 * i] = 0.f;

  // ---- staging: 32 reps-rows x 256B -> 8KB buffer; linear LDS dest,
  //      4-bit XOR pre-swizzled source (read-side involution) ----
  auto stage = [&](int bufi, int colbase) {
#pragma unroll
    for (int i = 0; i < 8; ++i) {
      int lr = i * 4 + (l >> 4);     // local row 0..31
      int kb = ((l & 15) * 16) ^ ((lr & 15) << 4);
      gload_lds16((const char*)reps_ + (size_t)(colbase + lr) * 256 + kb,
                  (void*)&smem[bufi][i * 64]);
    }
  };
  stage(0, cs0);

  // ---- A fragments: 64-row strip; lane holds row rowbase+fr*16+(l&15) ----
  i32x4 a[4][4];
  {
    const uint4* r4 = (const uint4*)reps_;
    int arow = rowbase + (l & 15);
#pragma unroll
    for (int fr = 0; fr < 4; ++fr)
#pragma unroll
      for (int kk = 0; kk < 4; ++kk)
        a[fr][kk] = __builtin_bit_cast(i32x4,
            r4[(size_t)(arow + fr * 16) * 16 + kk * 4 + kgrp]);
  }

  float rowsum[4][4];
#pragma unroll
  for (int fr = 0; fr < 4; ++fr)
#pragma unroll
    for (int r = 0; r < 4; ++r) rowsum[fr][r] = 0.f;

  int r0 = rowbase + kgrp * 4;
  int buf = 0;
  const int kmad = KMAD;             // SGPR
  const int cbits = CBITS;           // VGPR (2nd const; 1-SGPR rule)

  for (int t = 0; t < ntile; ++t) {
    if (t + 1 < ntile) {
      stage(buf ^ 1, cs0 + 32 * (t + 1));
      asm volatile("s_waitcnt vmcnt(8)" ::: "memory");
    } else {
      asm volatile("s_waitcnt vmcnt(0)" ::: "memory");
    }
    __builtin_amdgcn_sched_barrier(0);

    const char* bb = (const char*)&smem[0][0] + buf * 8192;
    i32x4 acc[4][2];
    const i32x4 zero = {0, 0, 0, 0};
    __builtin_amdgcn_s_setprio(1);
#pragma unroll
    for (int kk = 0; kk < 4; ++kk) {
      i32x4 bf[2];
#pragma unroll
      for (int fc = 0; fc < 2; ++fc) {
        int lr = (l & 15) + fc * 16;
        bf[fc] = *(const i32x4*)(bb + lr * 256 + ((((kk * 4 + kgrp) ^ (lr & 15))) << 4));
      }
#pragma unroll
      for (int fr = 0; fr < 4; ++fr)
#pragma unroll
        for (int fc = 0; fc < 2; ++fc) {
          if (kk == 0)
            acc[fr][fc] = __builtin_amdgcn_mfma_i32_16x16x64_i8(a[fr][0], bf[fc], zero, 0, 0, 0);
          else
            acc[fr][fc] = __builtin_amdgcn_mfma_i32_16x16x64_i8(a[fr][kk], bf[fc], acc[fr][fc], 0, 0, 0);
        }
    }
    __builtin_amdgcn_s_setprio(0);

    // ---- epilogue: e = bitcast(mad_i24(I, K, C)); rowsum + colacc (LDS) ----
    int cb = cs0 + 32 * t;
    bool docol = !(q == 0 && t < 2);        // diag 64-col window: rowsum only
    bool dopos = (q == 16) && (t < 2);
    float cp0 = 0.f, cp1 = 0.f;
#pragma unroll
    for (int fr = 0; fr < 4; ++fr)
#pragma unroll
      for (int fc = 0; fc < 2; ++fc)
#pragma unroll
        for (int r = 0; r < 4; ++r) {
          int I = acc[fr][fc][r];
          int ib;
          asm("v_mad_i32_i24 %0, %1, %2, %3"
              : "=v"(ib) : "v"(I), "s"(kmad), "v"(cbits));
          float e = __builtin_bit_cast(float, ib);
          if (dopos) {
            int rg = r0 + fr * 16 + r;
            int cg = cb + (l & 15) + fc * 16;
            if (cg == rg + BROWS) pos[rg] = (float)I * FSC;
          }
          rowsum[fr][r] += e;
          if (fc == 0) cp0 += e; else cp1 += e;
        }
    if (docol) {
      cp0 += __shfl_xor(cp0, 16, 64); cp0 += __shfl_xor(cp0, 32, 64);
      cp1 += __shfl_xor(cp1, 16, 64); cp1 += __shfl_xor(cp1, 32, 64);
      if (l < 16) {
        int off = (cb - cs0) + l;
        colacc[off] += cp0;
        colacc[off + 16] += cp1;
      }
    }
    buf ^= 1;
  }

  // ---- row sums: reduce 16 col-lanes; 4 lanes issue global atomics ----
#pragma unroll
  for (int fr = 0; fr < 4; ++fr)
#pragma unroll
    for (int r = 0; r < 4; ++r) {
      float vv = rowsum[fr][r];
      vv += __shfl_xor(vv, 1, 64);
      vv += __shfl_xor(vv, 2, 64);
      vv += __shfl_xor(vv, 4, 64);
      vv += __shfl_xor(vv, 8, 64);
      if ((l & 15) == 0) atomicAdd(&denom[r0 + fr * 16 + r], vv);
    }

  // ---- col sums: flush colacc, one atomic per nonzero column ----
#pragma unroll
  for (int i = 0; i < 4; ++i) {
    int off = l + 64 * i;
    float vv = colacc[off];
    if (vv != 0.f) atomicAdd(&denom[cs0 + off], vv);
  }
}

// Kernel F: subtract the (bit-identical) diagonal term, then
// + (1/N) * sum_i (log(denom_i) - pos_{i mod B} * ln2)
__global__ __launch_bounds__(256) void kfin(const float* __restrict__ denom,
                                            const float* __restrict__ pos,
                                            const int* __restrict__ qss,
                                            float* __restrict__ out) {
  int i = blockIdx.x * 256 + threadIdx.x;
  int ib = qss[i] * KMAD + CBITS;           // same int formula as ksim's mad_i24
  float diag_e = __builtin_bit_cast(float, ib);
  float v = (logf(denom[i] - diag_e) - pos[i & 4095] * LN2) * (1.0f / 8192.0f);
#pragma unroll
  for (int m = 1; m < 64; m <<= 1) v += __shfl_xor(v, m, 64);
  __shared__ float part[4];
  if ((threadIdx.x & 63) == 0) part[threadIdx.x >> 6] = v;
  __syncthreads();
  if (threadIdx.x == 0)
    atomicAdd(out, part[0] + part[1] + part[2] + part[3]);
}

extern "C" void kernel_launch(void* const* d_in, const int* in_sizes, int n_in,
                              void* d_out, int out_size, void* d_ws, size_t ws_size,
                              hipStream_t stream) {
  (void)in_sizes; (void)n_in; (void)out_size; (void)ws_size;
  const float* zi = (const float*)d_in[0];
  const float* zj = (const float*)d_in[1];
  float* out = (float*)d_out;
  char* ws = (char*)d_ws;
  int* reps    = (int*)ws;                                    // 2 MB (i8 packed)
  float* denom = (float*)(ws + 2097152);                      // 32 KB
  float* pos   = (float*)(ws + 2097152 + 32768);              // 16 KB
  int* qss     = (int*)(ws + 2097152 + 32768 + 16384);        // 32 KB
  int* tab     = (int*)(ws + 2097152 + 32768 + 16384 + 32768); // 8.25 KB

  knorm<<<2048, 256, 0, stream>>>(zi, zj, reps, qss, tab, denom, out);
  ksim<<<NBLK, 64, 0, stream>>>(reps, tab, denom, pos);
  kfin<<<32, 256, 0, stream>>>(denom, pos, qss, out);
}

// Round 23
// 37.914 us; speedup vs baseline: 1.4247x; 1.0690x over previous
//
#include <hip/hip_runtime.h>
#include <hip/hip_bf16.h>
#include <stdint.h>

#define NROWS 8192
#define BROWS 4096
#define LN2 0.6931471805599453f
#define FSC 8.944507e-4f        // (1/T)*log2(e) / 127^2, T=0.1
#define KMAD 7503               // round(FSC * 2^23)
#define CBITS 1064989150        // (127 - 0.0434) * 2^23  (Schraudolph exp2)
#define NBLK 2112               // sum_{it=0}^{127} ceil((128-it)/4) = 8*264

typedef __attribute__((ext_vector_type(4))) int i32x4;

__device__ inline void gload_lds16(const void* g, void* l) {
  __builtin_amdgcn_global_load_lds((const __attribute__((address_space(1))) void*)g,
                                   (__attribute__((address_space(3))) void*)l,
                                   16, 0, 0);
}

// C(it) = number of blocks before strip it (exact): 2112 - S(132-it),
// S(n) = sum_{k<n} (k>>2) = 2m(m-1) + r*m with m=n>>2, r=n&3.
__device__ inline int cum_blocks(int it) {
  int n = 132 - it, m = n >> 2, r = n & 3;
  return NBLK - (2 * m * (m - 1) + r * m);
}

// Kernel A: L2-normalize rows, quantize to i8; store qss=sum(q^2); zero denom/out.
__global__ __launch_bounds__(256) void knorm(const float* __restrict__ zi,
                                             const float* __restrict__ zj,
                                             int* __restrict__ reps,   // i8 packed
                                             int* __restrict__ qss,
                                             float* __restrict__ denom,
                                             float* __restrict__ out) {
  int w = threadIdx.x >> 6, l = threadIdx.x & 63;
  int row = blockIdx.x * 4 + w;
  const float* src = (row < BROWS) ? (zi + (size_t)row * 256)
                                   : (zj + (size_t)(row - BROWS) * 256);
  float4 v = ((const float4*)src)[l];
  float ss = v.x * v.x + v.y * v.y + v.z * v.z + v.w * v.w;
#pragma unroll
  for (int m = 1; m < 64; m <<= 1) ss += __shfl_xor(ss, m, 64);
  float sc = 127.0f / fmaxf(sqrtf(ss), 1e-12f);
  int q0 = __float2int_rn(v.x * sc), q1 = __float2int_rn(v.y * sc);
  int q2 = __float2int_rn(v.z * sc), q3 = __float2int_rn(v.w * sc);
  reps[(size_t)row * 64 + l] =
      (q0 & 255) | ((q1 & 255) << 8) | ((q2 & 255) << 16) | ((q3 & 255) << 24);
  int qs = q0 * q0 + q1 * q1 + q2 * q2 + q3 * q3;
#pragma unroll
  for (int m = 1; m < 64; m <<= 1) qs += __shfl_xor(qs, m, 64);
  if (l == 0) { denom[row] = 0.f; qss[row] = qs; }
  if (row == 0 && l == 0) out[0] = 0.f;
}

// Kernel B: R16's structure (best measured) + closed-form decode + split vmcnt.
// Barrier-free upper-tri sim, i8 MFMA 16x16x64, ONE WAVE PER BLOCK.
// Block = 64-row strip x 256-col chunk (2112 blocks); 32-col dbuf LDS tiles
// (2x8KB). Per phase, stage(t)'s 8 loads retire in order, so vmcnt(12) gates
// rows 0-15 (fc=0 MFMAs) and vmcnt(8) gates rows 16-31 (fc=1) -- the exposed
// wait is halved. Schraudolph exp2 epilogue; diag subtracted in kfin.
__global__ __launch_bounds__(64, 2) void ksim(const int* __restrict__ reps_,
                                              float* __restrict__ denom,
                                              float* __restrict__ pos) {
  __shared__ uint4 smem[2][512];     // 2 x 32 reps-rows x 256 B = 16 KB
  __shared__ float colacc[256];      // 1 KB (single wave: plain adds)
  int l = threadIdx.x;               // 0..63
  int kgrp = l >> 4;

  // ---- closed-form block -> (strip it, chunk q); ALU only, no memory ----
  int b = blockIdx.x;
  int orig = (b & 7) * 264 + (b >> 3);     // XCD-bijective swizzle
  float f = 8.0f * (float)(NBLK - orig) + 0.25f;
  int it = 132 - (int)(sqrtf(f) + 0.5f);
  if (it < 0) it = 0;
  if (it > 127) it = 127;
  while (it < 127 && cum_blocks(it + 1) <= orig) ++it;
  while (it > 0 && cum_blocks(it) > orig) --it;
  int q = orig - cum_blocks(it);
  int rowbase = it * 64;
  int cs0 = rowbase + q * 256;
  int len = NROWS - cs0; if (len > 256) len = 256;
  int ntile = len >> 5;              // 2,4,6,8

#pragma unroll
  for (int i = 0; i < 4; ++i) colacc[l + 64 * i] = 0.f;

  // ---- staging: 32 reps-rows x 256B -> 8KB buffer; rows written in order
  //      (loads retire in order -> half-tile gating works); linear LDS dest,
  //      4-bit XOR pre-swizzled source ----
  auto stage = [&](int bufi, int colbase) {
#pragma unroll
    for (int i = 0; i < 8; ++i) {
      int lr = i * 4 + (l >> 4);     // local row 0..31
      int kb = ((l & 15) * 16) ^ ((lr & 15) << 4);
      gload_lds16((const char*)reps_ + (size_t)(colbase + lr) * 256 + kb,
                  (void*)&smem[bufi][i * 64]);
    }
  };
  stage(0, cs0);

  // ---- A fragments: 64-row strip; lane holds row rowbase+fr*16+(l&15) ----
  i32x4 a[4][4];
  {
    const uint4* r4 = (const uint4*)reps_;
    int arow = rowbase + (l & 15);
#pragma unroll
    for (int fr = 0; fr < 4; ++fr)
#pragma unroll
      for (int kk = 0; kk < 4; ++kk)
        a[fr][kk] = __builtin_bit_cast(i32x4,
            r4[(size_t)(arow + fr * 16) * 16 + kk * 4 + kgrp]);
  }

  float rowsum[4][4];
#pragma unroll
  for (int fr = 0; fr < 4; ++fr)
#pragma unroll
    for (int r = 0; r < 4; ++r) rowsum[fr][r] = 0.f;

  int r0 = rowbase + kgrp * 4;
  int buf = 0;
  const int kmad = KMAD;             // SGPR
  const int cbits = CBITS;           // VGPR (2nd const; 1-SGPR rule)

  for (int t = 0; t < ntile; ++t) {
    bool hasNext = (t + 1 < ntile);
    if (hasNext) stage(buf ^ 1, cs0 + 32 * (t + 1));

    const char* bb = (const char*)&smem[0][0] + buf * 8192;
    i32x4 acc[4][2];
    const i32x4 zero = {0, 0, 0, 0};

    // half(fc): 4 ds_read + 16 MFMA into acc[*][fc]
    auto half = [&](int fc) {
      __builtin_amdgcn_s_setprio(1);
#pragma unroll
      for (int kk = 0; kk < 4; ++kk) {
        int lr = (l & 15) + fc * 16;
        i32x4 bf = *(const i32x4*)(bb + lr * 256 + ((((kk * 4 + kgrp) ^ (lr & 15))) << 4));
#pragma unroll
        for (int fr = 0; fr < 4; ++fr) {
          if (kk == 0)
            acc[fr][fc] = __builtin_amdgcn_mfma_i32_16x16x64_i8(a[fr][0], bf, zero, 0, 0, 0);
          else
            acc[fr][fc] = __builtin_amdgcn_mfma_i32_16x16x64_i8(a[fr][kk], bf, acc[fr][fc], 0, 0, 0);
        }
      }
      __builtin_amdgcn_s_setprio(0);
    };

    if (t == 0) {                      // A-frags force a full wait anyway
      asm volatile("s_waitcnt vmcnt(8)" ::: "memory");   // stage(0)+A done
      __builtin_amdgcn_sched_barrier(0);
      half(0); half(1);
    } else if (hasNext) {              // steady: stage(t) 8 + stage(t+1) 8 in flight
      asm volatile("s_waitcnt vmcnt(12)" ::: "memory");  // rows 0-15 of stage(t)
      __builtin_amdgcn_sched_barrier(0);
      half(0);
      asm volatile("s_waitcnt vmcnt(8)" ::: "memory");   // rows 16-31
      __builtin_amdgcn_sched_barrier(0);
      half(1);
    } else {                           // tail: only stage(t) 8 in flight
      asm volatile("s_waitcnt vmcnt(4)" ::: "memory");
      __builtin_amdgcn_sched_barrier(0);
      half(0);
      asm volatile("s_waitcnt vmcnt(0)" ::: "memory");
      __builtin_amdgcn_sched_barrier(0);
      half(1);
    }

    // ---- epilogue: e = bitcast(mad_i24(I, K, C)); rowsum + colacc (LDS) ----
    int cb = cs0 + 32 * t;
    bool docol = !(q == 0 && t < 2);        // diag 64-col window: rowsum only
    bool dopos = (q == 16) && (t < 2);
    float cp0 = 0.f, cp1 = 0.f;
#pragma unroll
    for (int fr = 0; fr < 4; ++fr)
#pragma unroll
      for (int fc = 0; fc < 2; ++fc)
#pragma unroll
        for (int r = 0; r < 4; ++r) {
          int I = acc[fr][fc][r];
          int ib;
          asm("v_mad_i32_i24 %0, %1, %2, %3"
              : "=v"(ib) : "v"(I), "s"(kmad), "v"(cbits));
          float e = __builtin_bit_cast(float, ib);
          if (dopos) {
            int rg = r0 + fr * 16 + r;
            int cg = cb + (l & 15) + fc * 16;
            if (cg == rg + BROWS) pos[rg] = (float)I * FSC;
          }
          rowsum[fr][r] += e;
          if (fc == 0) cp0 += e; else cp1 += e;
        }
    if (docol) {
      cp0 += __shfl_xor(cp0, 16, 64); cp0 += __shfl_xor(cp0, 32, 64);
      cp1 += __shfl_xor(cp1, 16, 64); cp1 += __shfl_xor(cp1, 32, 64);
      if (l < 16) {
        int off = (cb - cs0) + l;
        colacc[off] += cp0;
        colacc[off + 16] += cp1;
      }
    }
    buf ^= 1;
  }

  // ---- row sums: reduce 16 col-lanes; 4 lanes issue global atomics ----
#pragma unroll
  for (int fr = 0; fr < 4; ++fr)
#pragma unroll
    for (int r = 0; r < 4; ++r) {
      float vv = rowsum[fr][r];
      vv += __shfl_xor(vv, 1, 64);
      vv += __shfl_xor(vv, 2, 64);
      vv += __shfl_xor(vv, 4, 64);
      vv += __shfl_xor(vv, 8, 64);
      if ((l & 15) == 0) atomicAdd(&denom[r0 + fr * 16 + r], vv);
    }

  // ---- col sums: flush colacc, one atomic per nonzero column ----
#pragma unroll
  for (int i = 0; i < 4; ++i) {
    int off = l + 64 * i;
    float vv = colacc[off];
    if (vv != 0.f) atomicAdd(&denom[cs0 + off], vv);
  }
}

// Kernel F: subtract the (bit-identical) diagonal term, then
// + (1/N) * sum_i (log(denom_i) - pos_{i mod B} * ln2)
__global__ __launch_bounds__(256) void kfin(const float* __restrict__ denom,
                                            const float* __restrict__ pos,
                                            const int* __restrict__ qss,
                                            float* __restrict__ out) {
  int i = blockIdx.x * 256 + threadIdx.x;
  int ib = qss[i] * KMAD + CBITS;           // same int formula as ksim's mad_i24
  float diag_e = __builtin_bit_cast(float, ib);
  float v = (logf(denom[i] - diag_e) - pos[i & 4095] * LN2) * (1.0f / 8192.0f);
#pragma unroll
  for (int m = 1; m < 64; m <<= 1) v += __shfl_xor(v, m, 64);
  __shared__ float part[4];
  if ((threadIdx.x & 63) == 0) part[threadIdx.x >> 6] = v;
  __syncthreads();
  if (threadIdx.x == 0)
    atomicAdd(out, part[0] + part[1] + part[2] + part[3]);
}

extern "C" void kernel_launch(void* const* d_in, const int* in_sizes, int n_in,
                              void* d_out, int out_size, void* d_ws, size_t ws_size,
                              hipStream_t stream) {
  (void)in_sizes; (void)n_in; (void)out_size; (void)ws_size;
  const float* zi = (const float*)d_in[0];
  const float* zj = (const float*)d_in[1];
  float* out = (float*)d_out;
  char* ws = (char*)d_ws;
  int* reps    = (int*)ws;                                    // 2 MB (i8 packed)
  float* denom = (float*)(ws + 2097152);                      // 32 KB
  float* pos   = (float*)(ws + 2097152 + 32768);              // 16 KB
  int* qss     = (int*)(ws + 2097152 + 32768 + 16384);        // 32 KB

  knorm<<<2048, 256, 0, stream>>>(zi, zj, reps, qss, denom, out);
  ksim<<<NBLK, 64, 0, stream>>>(reps, denom, pos);
  kfin<<<32, 256, 0, stream>>>(denom, pos, qss, out);
}